// Round 1
// baseline (182.194 us; speedup 1.0000x reference)
//
#include <hip/hip_runtime.h>

// ---------- types ----------
typedef __bf16 v8bf __attribute__((ext_vector_type(8)));
typedef float  v4f  __attribute__((ext_vector_type(4)));
typedef unsigned short us8 __attribute__((ext_vector_type(8)));

// ---------- helpers ----------
__device__ __forceinline__ unsigned short f2bf(float f) {
  unsigned u = __builtin_bit_cast(unsigned, f);
  return (unsigned short)((u + 0x7FFFu + ((u >> 16) & 1u)) >> 16);
}
__device__ __forceinline__ float bf2f(unsigned short s) {
  return __builtin_bit_cast(float, (unsigned)s << 16);
}
__device__ __forceinline__ void gl_lds16(const void* g, void* l) {
  __builtin_amdgcn_global_load_lds(
      (__attribute__((address_space(1))) void*)(void*)g,
      (__attribute__((address_space(3))) void*)l, 16, 0, 0);
}

// ---------- conversion kernels ----------
// Split fp32 into bf16 hi/lo, writing a K-concatenated [rows][2304] layout.
// lo_slot==1 (for x):  [hi | lo | hi]
// lo_slot==2 (for Wp): [hi | hi | lo]
// Pairing per z-chunk: z0 hi*hi, z1 lo*hi, z2 hi*lo.
__global__ void split_hl(const float4* __restrict__ in, unsigned short* __restrict__ out,
                         int ncol4, int lo_slot) {
  const int i = blockIdx.x * blockDim.x + threadIdx.x;
  const float4 v = in[i];
  const int row = i / ncol4;
  const int col = (i - row * ncol4) * 4;
  ushort4 hi = make_ushort4(f2bf(v.x), f2bf(v.y), f2bf(v.z), f2bf(v.w));
  ushort4 lo = make_ushort4(f2bf(v.x - bf2f(hi.x)), f2bf(v.y - bf2f(hi.y)),
                            f2bf(v.z - bf2f(hi.z)), f2bf(v.w - bf2f(hi.w)));
  unsigned short* base = out + (size_t)row * 2304 + col;
  *(ushort4*)(base)        = hi;
  *(ushort4*)(base + 768)  = (lo_slot == 1) ? lo : hi;
  *(ushort4*)(base + 1536) = (lo_slot == 1) ? hi : lo;
}

__global__ void conv_bf16(const float4* __restrict__ in, ushort4* __restrict__ out) {
  const int i = blockIdx.x * blockDim.x + threadIdx.x;
  const float4 v = in[i];
  out[i] = make_ushort4(f2bf(v.x), f2bf(v.y), f2bf(v.z), f2bf(v.w));
}

// ---------- GEMM: C[m,n] (+)= sum_k A[m,k]*B[n,k], bf16 inputs, fp32 atomic accum ----------
// 128x128 tile, BK=32, 4 waves, 16x16x32 bf16 MFMA (verified gemm_bt NT layout).
// grid.z = split-K chunk; chunk z covers cols [z*Ksub, (z+1)*Ksub) of A/B.
// bias (per output col) added only by z==0 blocks (C must be pre-zeroed).
__global__ __launch_bounds__(256) void gemm_bt(
    const unsigned short* __restrict__ A, int lda,
    const unsigned short* __restrict__ B, int ldb,
    float* __restrict__ C, int ldc,
    int Ksub, int tilesN, const float* __restrict__ bias) {
  const int t = threadIdx.x;
  const int bm = blockIdx.x / tilesN;
  const int bn = blockIdx.x % tilesN;
  const int z  = blockIdx.z;
  A += (size_t)z * Ksub;
  B += (size_t)z * Ksub;

  const int wave = t >> 6, lane = t & 63;
  const int quad = lane >> 4, l16 = lane & 15;
  const int wm = (wave >> 1) * 64, wn = (wave & 1) * 64;

  __shared__ __align__(16) unsigned short As[128 * 32];
  __shared__ __align__(16) unsigned short Bs[128 * 32];

  const int srow = t >> 2;          // 0..63
  const int scol = (t & 3) * 8;     // 0,8,16,24
  const unsigned short* Ag = A + (size_t)(bm * 128 + srow) * lda + scol;
  const unsigned short* Bg = B + (size_t)(bn * 128 + srow) * ldb + scol;
  unsigned short* Al = &As[t * 8];
  unsigned short* Bl = &Bs[t * 8];

  v4f acc[4][4];
#pragma unroll
  for (int i = 0; i < 4; i++)
#pragma unroll
    for (int j = 0; j < 4; j++) acc[i][j] = (v4f){0.f, 0.f, 0.f, 0.f};

  for (int kt = 0; kt < Ksub; kt += 32) {
    gl_lds16(Ag + kt, Al);
    gl_lds16(Ag + (size_t)64 * lda + kt, Al + 2048);
    gl_lds16(Bg + kt, Bl);
    gl_lds16(Bg + (size_t)64 * ldb + kt, Bl + 2048);
    __syncthreads();
    v8bf af[4], bfr[4];
#pragma unroll
    for (int i = 0; i < 4; i++)
      af[i] = *(const v8bf*)&As[(wm + i * 16 + l16) * 32 + quad * 8];
#pragma unroll
    for (int j = 0; j < 4; j++)
      bfr[j] = *(const v8bf*)&Bs[(wn + j * 16 + l16) * 32 + quad * 8];
#pragma unroll
    for (int i = 0; i < 4; i++)
#pragma unroll
      for (int j = 0; j < 4; j++)
        acc[i][j] = __builtin_amdgcn_mfma_f32_16x16x32_bf16(af[i], bfr[j], acc[i][j], 0, 0, 0);
    __syncthreads();
  }

  const int row0 = bm * 128 + wm + quad * 4;
  const int col0 = bn * 128 + wn + l16;
#pragma unroll
  for (int j = 0; j < 4; j++) {
    const int col = col0 + j * 16;
    const float bv = (bias != nullptr && z == 0) ? bias[col] : 0.f;
#pragma unroll
    for (int i = 0; i < 4; i++) {
#pragma unroll
      for (int r = 0; r < 4; r++) {
        atomicAdd(&C[(size_t)(row0 + i * 16 + r) * ldc + col], acc[i][j][r] + bv);
      }
    }
  }
}

// ---------- quantum head: angles -> PauliZ expectations (closed form) ----------
// expz[0] = prod_{j=1..7} cos(theta_j); expz[w>=1] = prod_{j=0..w} cos(theta_j)
__global__ void quantum_head(const float* __restrict__ proj,
                             const float* __restrict__ b_proj,
                             const float* __restrict__ theta,
                             unsigned short* __restrict__ EZ) {
  const int h = blockIdx.x * blockDim.x + threadIdx.x;  // 0..4096*96-1
  const int token = h / 96;
  const int head = h - token * 96;
  const float* p  = proj + (size_t)token * 768 + head * 8;
  const float* bp = b_proj + head * 8;
  const float4 p0 = *(const float4*)p;
  const float4 p1 = *(const float4*)(p + 4);
  const float4 b0 = *(const float4*)bp;
  const float4 b1 = *(const float4*)(bp + 4);
  float c[8];
  c[0] = cosf(p0.x + b0.x + theta[0]);
  c[1] = cosf(p0.y + b0.y + theta[1]);
  c[2] = cosf(p0.z + b0.z + theta[2]);
  c[3] = cosf(p0.w + b0.w + theta[3]);
  c[4] = cosf(p1.x + b1.x + theta[4]);
  c[5] = cosf(p1.y + b1.y + theta[5]);
  c[6] = cosf(p1.z + b1.z + theta[6]);
  c[7] = cosf(p1.w + b1.w + theta[7]);
  float e[8];
  e[0] = c[1] * c[2] * c[3] * c[4] * c[5] * c[6] * c[7];
  float pr = c[0];
#pragma unroll
  for (int w = 1; w < 8; w++) { pr *= c[w]; e[w] = pr; }
  us8 ov;
#pragma unroll
  for (int w = 0; w < 8; w++) ov[w] = f2bf(e[w]);
  *(us8*)(EZ + (size_t)h * 8) = ov;
}

// ---------- launch ----------
extern "C" void kernel_launch(void* const* d_in, const int* in_sizes, int n_in,
                              void* d_out, int out_size, void* d_ws, size_t ws_size,
                              hipStream_t stream) {
  const float* x     = (const float*)d_in[0];
  const float* Wp    = (const float*)d_in[1];
  const float* bp    = (const float*)d_in[2];
  const float* theta = (const float*)d_in[3];
  const float* Wcf   = (const float*)d_in[4];
  const float* bc    = (const float*)d_in[5];
  float* out = (float*)d_out;

  const int M = 4096, E = 768;

  unsigned short* XC = (unsigned short*)d_ws;        // [4096][2304] bf16  (x: hi|lo|hi)
  unsigned short* WC = XC + (size_t)M * 2304;        // [768][2304] bf16   (Wp: hi|hi|lo)
  unsigned short* WB = WC + (size_t)E * 2304;        // [768][768] bf16    (W_comb)
  unsigned short* EZ = WB + (size_t)E * E;           // [4096][768] bf16   (expz)
  float* proj        = (float*)(EZ + (size_t)M * E); // [4096][768] fp32

  hipMemsetAsync(proj, 0, (size_t)M * E * sizeof(float), stream);
  hipMemsetAsync(out, 0, (size_t)M * E * sizeof(float), stream);

  // conversions
  split_hl<<<3072, 256, 0, stream>>>((const float4*)x, XC, 192, 1);   // 4096*768/4 threads
  split_hl<<<576, 256, 0, stream>>>((const float4*)Wp, WC, 192, 2);   // 768*768/4
  conv_bf16<<<576, 256, 0, stream>>>((const float4*)Wcf, (ushort4*)WB);

  // GEMM1: proj = x @ Wp^T  (hi/lo split as split-K over 3 chunks of 768)
  gemm_bt<<<dim3(192, 1, 3), 256, 0, stream>>>(XC, 2304, WC, 2304, proj, 768, 768, 6, nullptr);

  // quantum head: angles = proj + b_proj + theta -> expz (bf16)
  quantum_head<<<1536, 256, 0, stream>>>(proj, bp, theta, EZ);

  // GEMM2: out = expz @ Wc^T + bc  (split-K over 3 chunks of 256)
  gemm_bt<<<dim3(192, 1, 3), 256, 0, stream>>>(EZ, 768, WB, 768, out, 768, 256, 6, bc);
}

// Round 2
// 163.231 us; speedup vs baseline: 1.1162x; 1.1162x over previous
//
#include <hip/hip_runtime.h>

// ---------- types ----------
typedef __bf16 v8bf __attribute__((ext_vector_type(8)));
typedef float  v4f  __attribute__((ext_vector_type(4)));
typedef unsigned short us8 __attribute__((ext_vector_type(8)));

// ---------- helpers ----------
__device__ __forceinline__ unsigned short f2bf(float f) {
  unsigned u = __builtin_bit_cast(unsigned, f);
  return (unsigned short)((u + 0x7FFFu + ((u >> 16) & 1u)) >> 16);
}
__device__ __forceinline__ float bf2f(unsigned short s) {
  return __builtin_bit_cast(float, (unsigned)s << 16);
}
__device__ __forceinline__ void gl_lds16(const void* g, void* l) {
  __builtin_amdgcn_global_load_lds(
      (__attribute__((address_space(1))) void*)(void*)g,
      (__attribute__((address_space(3))) void*)l, 16, 0, 0);
}

// ---------- conversion kernels ----------
// Split fp32 into bf16 hi/lo, writing a K-concatenated [rows][2304] layout.
// lo_slot==1 (for x):  [hi | lo | hi]
// lo_slot==2 (for Wp): [hi | hi | lo]
// Single-GEMM K=2304 dot = x_hi*W_hi + x_lo*W_hi + x_hi*W_lo.
__global__ void split_hl(const float4* __restrict__ in, unsigned short* __restrict__ out,
                         int ncol4, int lo_slot) {
  const int i = blockIdx.x * blockDim.x + threadIdx.x;
  const float4 v = in[i];
  const int row = i / ncol4;
  const int col = (i - row * ncol4) * 4;
  ushort4 hi = make_ushort4(f2bf(v.x), f2bf(v.y), f2bf(v.z), f2bf(v.w));
  ushort4 lo = make_ushort4(f2bf(v.x - bf2f(hi.x)), f2bf(v.y - bf2f(hi.y)),
                            f2bf(v.z - bf2f(hi.z)), f2bf(v.w - bf2f(hi.w)));
  unsigned short* base = out + (size_t)row * 2304 + col;
  *(ushort4*)(base)        = hi;
  *(ushort4*)(base + 768)  = (lo_slot == 1) ? lo : hi;
  *(ushort4*)(base + 1536) = (lo_slot == 1) ? hi : lo;
}

__global__ void conv_bf16(const float4* __restrict__ in, ushort4* __restrict__ out) {
  const int i = blockIdx.x * blockDim.x + threadIdx.x;
  const float4 v = in[i];
  out[i] = make_ushort4(f2bf(v.x), f2bf(v.y), f2bf(v.z), f2bf(v.w));
}

// ---------- GEMM: C[m,n] = sum_k A[m,k]*B[n,k] (+bias[n]), bf16 in, fp32 out ----------
// 128x128 tile, BK=32, 4 waves, 16x16x32 bf16 MFMA (verified gemm_bt NT layout).
// Single K sweep, in-register fp32 accumulation, direct (non-atomic) store.
__global__ __launch_bounds__(256) void gemm_bt(
    const unsigned short* __restrict__ A, int lda,
    const unsigned short* __restrict__ B, int ldb,
    float* __restrict__ C, int ldc,
    int K, int tilesN, const float* __restrict__ bias) {
  const int t = threadIdx.x;
  const int bm = blockIdx.x / tilesN;
  const int bn = blockIdx.x % tilesN;

  const int wave = t >> 6, lane = t & 63;
  const int quad = lane >> 4, l16 = lane & 15;
  const int wm = (wave >> 1) * 64, wn = (wave & 1) * 64;

  __shared__ __align__(16) unsigned short As[128 * 32];
  __shared__ __align__(16) unsigned short Bs[128 * 32];

  const int srow = t >> 2;          // 0..63
  const int scol = (t & 3) * 8;     // 0,8,16,24
  const unsigned short* Ag = A + (size_t)(bm * 128 + srow) * lda + scol;
  const unsigned short* Bg = B + (size_t)(bn * 128 + srow) * ldb + scol;
  unsigned short* Al = &As[t * 8];
  unsigned short* Bl = &Bs[t * 8];

  v4f acc[4][4];
#pragma unroll
  for (int i = 0; i < 4; i++)
#pragma unroll
    for (int j = 0; j < 4; j++) acc[i][j] = (v4f){0.f, 0.f, 0.f, 0.f};

  for (int kt = 0; kt < K; kt += 32) {
    gl_lds16(Ag + kt, Al);
    gl_lds16(Ag + (size_t)64 * lda + kt, Al + 2048);
    gl_lds16(Bg + kt, Bl);
    gl_lds16(Bg + (size_t)64 * ldb + kt, Bl + 2048);
    __syncthreads();
    v8bf af[4], bfr[4];
#pragma unroll
    for (int i = 0; i < 4; i++)
      af[i] = *(const v8bf*)&As[(wm + i * 16 + l16) * 32 + quad * 8];
#pragma unroll
    for (int j = 0; j < 4; j++)
      bfr[j] = *(const v8bf*)&Bs[(wn + j * 16 + l16) * 32 + quad * 8];
#pragma unroll
    for (int i = 0; i < 4; i++)
#pragma unroll
      for (int j = 0; j < 4; j++)
        acc[i][j] = __builtin_amdgcn_mfma_f32_16x16x32_bf16(af[i], bfr[j], acc[i][j], 0, 0, 0);
    __syncthreads();
  }

  const int row0 = bm * 128 + wm + quad * 4;
  const int col0 = bn * 128 + wn + l16;
#pragma unroll
  for (int j = 0; j < 4; j++) {
    const int col = col0 + j * 16;
    const float bv = bias ? bias[col] : 0.f;
#pragma unroll
    for (int i = 0; i < 4; i++) {
#pragma unroll
      for (int r = 0; r < 4; r++) {
        C[(size_t)(row0 + i * 16 + r) * ldc + col] = acc[i][j][r] + bv;
      }
    }
  }
}

// ---------- quantum head: angles -> PauliZ expectations (closed form) ----------
// expz[0] = prod_{j=1..7} cos(theta_j); expz[w>=1] = prod_{j=0..w} cos(theta_j)
__global__ void quantum_head(const float* __restrict__ proj,
                             const float* __restrict__ b_proj,
                             const float* __restrict__ theta,
                             unsigned short* __restrict__ EZ) {
  const int h = blockIdx.x * blockDim.x + threadIdx.x;  // 0..4096*96-1
  const int token = h / 96;
  const int head = h - token * 96;
  const float* p  = proj + (size_t)token * 768 + head * 8;
  const float* bp = b_proj + head * 8;
  const float4 p0 = *(const float4*)p;
  const float4 p1 = *(const float4*)(p + 4);
  const float4 b0 = *(const float4*)bp;
  const float4 b1 = *(const float4*)(bp + 4);
  float c[8];
  c[0] = cosf(p0.x + b0.x + theta[0]);
  c[1] = cosf(p0.y + b0.y + theta[1]);
  c[2] = cosf(p0.z + b0.z + theta[2]);
  c[3] = cosf(p0.w + b0.w + theta[3]);
  c[4] = cosf(p1.x + b1.x + theta[4]);
  c[5] = cosf(p1.y + b1.y + theta[5]);
  c[6] = cosf(p1.z + b1.z + theta[6]);
  c[7] = cosf(p1.w + b1.w + theta[7]);
  float e[8];
  e[0] = c[1] * c[2] * c[3] * c[4] * c[5] * c[6] * c[7];
  float pr = c[0];
#pragma unroll
  for (int w = 1; w < 8; w++) { pr *= c[w]; e[w] = pr; }
  us8 ov;
#pragma unroll
  for (int w = 0; w < 8; w++) ov[w] = f2bf(e[w]);
  *(us8*)(EZ + (size_t)h * 8) = ov;
}

// ---------- launch ----------
extern "C" void kernel_launch(void* const* d_in, const int* in_sizes, int n_in,
                              void* d_out, int out_size, void* d_ws, size_t ws_size,
                              hipStream_t stream) {
  const float* x     = (const float*)d_in[0];
  const float* Wp    = (const float*)d_in[1];
  const float* bp    = (const float*)d_in[2];
  const float* theta = (const float*)d_in[3];
  const float* Wcf   = (const float*)d_in[4];
  const float* bc    = (const float*)d_in[5];
  float* out = (float*)d_out;

  const int M = 4096, E = 768;

  unsigned short* XC = (unsigned short*)d_ws;        // [4096][2304] bf16  (x: hi|lo|hi)
  unsigned short* WC = XC + (size_t)M * 2304;        // [768][2304] bf16   (Wp: hi|hi|lo)
  unsigned short* WB = WC + (size_t)E * 2304;        // [768][768] bf16    (W_comb)
  unsigned short* EZ = WB + (size_t)E * E;           // [4096][768] bf16   (expz)
  float* proj        = (float*)(EZ + (size_t)M * E); // [4096][768] fp32

  // conversions
  split_hl<<<3072, 256, 0, stream>>>((const float4*)x, XC, 192, 1);   // 4096*768/4 threads
  split_hl<<<576, 256, 0, stream>>>((const float4*)Wp, WC, 192, 2);   // 768*768/4
  conv_bf16<<<576, 256, 0, stream>>>((const float4*)Wcf, (ushort4*)WB);

  // GEMM1: proj = x @ Wp^T   (hi/lo via K-concat, K=2304, single sweep, no atomics)
  gemm_bt<<<dim3(32 * 6), 256, 0, stream>>>(XC, 2304, WC, 2304, proj, 768, 2304, 6, nullptr);

  // quantum head: angles = proj + b_proj + theta -> expz (bf16)
  quantum_head<<<1536, 256, 0, stream>>>(proj, bp, theta, EZ);

  // GEMM2: out = expz @ Wc^T + bc   (K=768, direct store + bias)
  gemm_bt<<<dim3(32 * 6), 256, 0, stream>>>(EZ, 768, WB, 768, out, 768, 768, 6, bc);
}

// Round 4
// 140.344 us; speedup vs baseline: 1.2982x; 1.1631x over previous
//
#include <hip/hip_runtime.h>

// ---------- types ----------
typedef __bf16 v8bf __attribute__((ext_vector_type(8)));
typedef float  v4f  __attribute__((ext_vector_type(4)));
typedef unsigned short us8 __attribute__((ext_vector_type(8)));

// ---------- helpers ----------
__device__ __forceinline__ unsigned short f2bf(float f) {
  unsigned u = __builtin_bit_cast(unsigned, f);
  return (unsigned short)((u + 0x7FFFu + ((u >> 16) & 1u)) >> 16);
}
__device__ __forceinline__ float bf2f(unsigned short s) {
  return __builtin_bit_cast(float, (unsigned)s << 16);
}
__device__ __forceinline__ void gl_lds16(const void* g, void* l) {
  __builtin_amdgcn_global_load_lds(
      (__attribute__((address_space(1))) void*)(void*)g,
      (__attribute__((address_space(3))) void*)l, 16, 0, 0);
}

// ---------- conversion kernels ----------
// Split fp32 into bf16 hi/lo, writing a K-concatenated [rows][2304] layout.
// lo_slot==1 (for x):  [hi | lo | hi]
// lo_slot==2 (for Wp): [hi | hi | lo]
// Single-GEMM K=2304 dot = x_hi*W_hi + x_lo*W_hi + x_hi*W_lo.
__global__ void split_hl(const float4* __restrict__ in, unsigned short* __restrict__ out,
                         int ncol4, int lo_slot) {
  const int i = blockIdx.x * blockDim.x + threadIdx.x;
  const float4 v = in[i];
  const int row = i / ncol4;
  const int col = (i - row * ncol4) * 4;
  ushort4 hi = make_ushort4(f2bf(v.x), f2bf(v.y), f2bf(v.z), f2bf(v.w));
  ushort4 lo = make_ushort4(f2bf(v.x - bf2f(hi.x)), f2bf(v.y - bf2f(hi.y)),
                            f2bf(v.z - bf2f(hi.z)), f2bf(v.w - bf2f(hi.w)));
  unsigned short* base = out + (size_t)row * 2304 + col;
  *(ushort4*)(base)        = hi;
  *(ushort4*)(base + 768)  = (lo_slot == 1) ? lo : hi;
  *(ushort4*)(base + 1536) = (lo_slot == 1) ? hi : lo;
}

__global__ void conv_bf16(const float4* __restrict__ in, ushort4* __restrict__ out) {
  const int i = blockIdx.x * blockDim.x + threadIdx.x;
  const float4 v = in[i];
  out[i] = make_ushort4(f2bf(v.x), f2bf(v.y), f2bf(v.z), f2bf(v.w));
}

// ---------- GEMM: C[m,n] = sum_k A[m,k]*B[n,k] (+bias[n]), bf16 in, fp32 out ----------
// 64x64 tile, BK=32, 4 waves (each wave: 32x32 via 2x2 of 16x16x32 MFMA).
// Grid is fixed at 64 M-tiles x 12 N-tiles = 768 blocks (3 blocks/CU -> 12 waves/CU
// for latency hiding). XCD-aware swizzle: xcd = blockIdx%8 (round-robin heuristic);
// each XCD gets a contiguous range of 8 M-tiles with N inner for A/B L2 locality.
__global__ __launch_bounds__(256) void gemm_bt64(
    const unsigned short* __restrict__ A, int lda,
    const unsigned short* __restrict__ B, int ldb,
    float* __restrict__ C, int ldc,
    int K, const float* __restrict__ bias) {
  const int t = threadIdx.x;
  const int b = blockIdx.x;
  const int xcd = b & 7, slot = b >> 3;      // 768 blocks -> slot 0..95
  const int bm = xcd * 8 + slot / 12;        // 0..63 (contiguous 8-M-tile band per XCD)
  const int bn = slot % 12;                  // 0..11

  const int wave = t >> 6, lane = t & 63;
  const int quad = lane >> 4, l16 = lane & 15;
  const int wm = (wave >> 1) * 32, wn = (wave & 1) * 32;

  __shared__ __align__(16) unsigned short As[64 * 32];
  __shared__ __align__(16) unsigned short Bs[64 * 32];

  const int srow = t >> 2;          // 0..63
  const int scol = (t & 3) * 8;     // 0,8,16,24
  const unsigned short* Ag = A + (size_t)(bm * 64 + srow) * lda + scol;
  const unsigned short* Bg = B + (size_t)(bn * 64 + srow) * ldb + scol;
  unsigned short* Al = &As[t * 8];
  unsigned short* Bl = &Bs[t * 8];

  v4f acc[2][2];
#pragma unroll
  for (int i = 0; i < 2; i++)
#pragma unroll
    for (int j = 0; j < 2; j++) acc[i][j] = (v4f){0.f, 0.f, 0.f, 0.f};

  for (int kt = 0; kt < K; kt += 32) {
    gl_lds16(Ag + kt, Al);
    gl_lds16(Bg + kt, Bl);
    __syncthreads();
    v8bf af[2], bfr[2];
#pragma unroll
    for (int i = 0; i < 2; i++)
      af[i] = *(const v8bf*)&As[(wm + i * 16 + l16) * 32 + quad * 8];
#pragma unroll
    for (int j = 0; j < 2; j++)
      bfr[j] = *(const v8bf*)&Bs[(wn + j * 16 + l16) * 32 + quad * 8];
#pragma unroll
    for (int i = 0; i < 2; i++)
#pragma unroll
      for (int j = 0; j < 2; j++)
        acc[i][j] = __builtin_amdgcn_mfma_f32_16x16x32_bf16(af[i], bfr[j], acc[i][j], 0, 0, 0);
    __syncthreads();
  }

  const int row0 = bm * 64 + wm + quad * 4;
  const int col0 = bn * 64 + wn + l16;
#pragma unroll
  for (int j = 0; j < 2; j++) {
    const int col = col0 + j * 16;
    const float bv = bias ? bias[col] : 0.f;
#pragma unroll
    for (int i = 0; i < 2; i++) {
#pragma unroll
      for (int r = 0; r < 4; r++) {
        C[(size_t)(row0 + i * 16 + r) * ldc + col] = acc[i][j][r] + bv;
      }
    }
  }
}

// ---------- quantum head: angles -> PauliZ expectations (closed form) ----------
// expz[0] = prod_{j=1..7} cos(theta_j); expz[w>=1] = prod_{j=0..w} cos(theta_j)
__global__ void quantum_head(const float* __restrict__ proj,
                             const float* __restrict__ b_proj,
                             const float* __restrict__ theta,
                             unsigned short* __restrict__ EZ) {
  const int h = blockIdx.x * blockDim.x + threadIdx.x;  // 0..4096*96-1
  const int token = h / 96;
  const int head = h - token * 96;
  const float* p  = proj + (size_t)token * 768 + head * 8;
  const float* bp = b_proj + head * 8;
  const float4 p0 = *(const float4*)p;
  const float4 p1 = *(const float4*)(p + 4);
  const float4 b0 = *(const float4*)bp;
  const float4 b1 = *(const float4*)(bp + 4);
  float c[8];
  c[0] = cosf(p0.x + b0.x + theta[0]);
  c[1] = cosf(p0.y + b0.y + theta[1]);
  c[2] = cosf(p0.z + b0.z + theta[2]);
  c[3] = cosf(p0.w + b0.w + theta[3]);
  c[4] = cosf(p1.x + b1.x + theta[4]);
  c[5] = cosf(p1.y + b1.y + theta[5]);
  c[6] = cosf(p1.z + b1.z + theta[6]);
  c[7] = cosf(p1.w + b1.w + theta[7]);
  float e[8];
  e[0] = c[1] * c[2] * c[3] * c[4] * c[5] * c[6] * c[7];
  float pr = c[0];
#pragma unroll
  for (int w = 1; w < 8; w++) { pr *= c[w]; e[w] = pr; }
  us8 ov;
#pragma unroll
  for (int w = 0; w < 8; w++) ov[w] = f2bf(e[w]);
  *(us8*)(EZ + (size_t)h * 8) = ov;
}

// ---------- launch ----------
extern "C" void kernel_launch(void* const* d_in, const int* in_sizes, int n_in,
                              void* d_out, int out_size, void* d_ws, size_t ws_size,
                              hipStream_t stream) {
  const float* x     = (const float*)d_in[0];
  const float* Wp    = (const float*)d_in[1];
  const float* bp    = (const float*)d_in[2];
  const float* theta = (const float*)d_in[3];
  const float* Wcf   = (const float*)d_in[4];
  const float* bc    = (const float*)d_in[5];
  float* out = (float*)d_out;

  const int M = 4096, E = 768;

  unsigned short* XC = (unsigned short*)d_ws;        // [4096][2304] bf16  (x: hi|lo|hi)
  unsigned short* WC = XC + (size_t)M * 2304;        // [768][2304] bf16   (Wp: hi|hi|lo)
  unsigned short* WB = WC + (size_t)E * 2304;        // [768][768] bf16    (W_comb)
  unsigned short* EZ = WB + (size_t)E * E;           // [4096][768] bf16   (expz)
  float* proj        = (float*)(EZ + (size_t)M * E); // [4096][768] fp32

  // conversions
  split_hl<<<3072, 256, 0, stream>>>((const float4*)x, XC, 192, 1);   // 4096*768/4 threads
  split_hl<<<576, 256, 0, stream>>>((const float4*)Wp, WC, 192, 2);   // 768*768/4
  conv_bf16<<<576, 256, 0, stream>>>((const float4*)Wcf, (ushort4*)WB);

  // GEMM1: proj = x @ Wp^T   (hi/lo via K-concat, K=2304)  64x12 tiles = 768 blocks
  gemm_bt64<<<768, 256, 0, stream>>>(XC, 2304, WC, 2304, proj, 768, 2304, nullptr);

  // quantum head: angles = proj + b_proj + theta -> expz (bf16)
  quantum_head<<<1536, 256, 0, stream>>>(proj, bp, theta, EZ);

  // GEMM2: out = expz @ Wc^T + bc   (K=768)  768 blocks
  gemm_bt64<<<768, 256, 0, stream>>>(EZ, 768, WB, 768, out, 768, 768, bc);
}

// Round 5
// 137.978 us; speedup vs baseline: 1.3205x; 1.0171x over previous
//
#include <hip/hip_runtime.h>

// ---------- types ----------
typedef __bf16 v8bf __attribute__((ext_vector_type(8)));
typedef float  v4f  __attribute__((ext_vector_type(4)));
typedef unsigned short us8 __attribute__((ext_vector_type(8)));

// ---------- helpers ----------
__device__ __forceinline__ unsigned short f2bf(float f) {
  unsigned u = __builtin_bit_cast(unsigned, f);
  return (unsigned short)((u + 0x7FFFu + ((u >> 16) & 1u)) >> 16);
}
__device__ __forceinline__ float bf2f(unsigned short s) {
  return __builtin_bit_cast(float, (unsigned)s << 16);
}

// ---------- conversion kernels ----------
// Split fp32 into bf16 hi/lo, writing a K-concatenated [rows][2304] layout.
// lo_slot==1 (for x):  [hi | lo | hi]
// lo_slot==2 (for Wp): [hi | hi | lo]
// Single-GEMM K=2304 dot = x_hi*W_hi + x_lo*W_hi + x_hi*W_lo.
__global__ void split_hl(const float4* __restrict__ in, unsigned short* __restrict__ out,
                         int ncol4, int lo_slot) {
  const int i = blockIdx.x * blockDim.x + threadIdx.x;
  const float4 v = in[i];
  const int row = i / ncol4;
  const int col = (i - row * ncol4) * 4;
  ushort4 hi = make_ushort4(f2bf(v.x), f2bf(v.y), f2bf(v.z), f2bf(v.w));
  ushort4 lo = make_ushort4(f2bf(v.x - bf2f(hi.x)), f2bf(v.y - bf2f(hi.y)),
                            f2bf(v.z - bf2f(hi.z)), f2bf(v.w - bf2f(hi.w)));
  unsigned short* base = out + (size_t)row * 2304 + col;
  *(ushort4*)(base)        = hi;
  *(ushort4*)(base + 768)  = (lo_slot == 1) ? lo : hi;
  *(ushort4*)(base + 1536) = (lo_slot == 1) ? hi : lo;
}

__global__ void conv_bf16(const float4* __restrict__ in, ushort4* __restrict__ out) {
  const int i = blockIdx.x * blockDim.x + threadIdx.x;
  const float4 v = in[i];
  out[i] = make_ushort4(f2bf(v.x), f2bf(v.y), f2bf(v.z), f2bf(v.w));
}

// ---------- GEMM: C[m,n] = sum_k A[m,k]*B[n,k] (+bias[n]), bf16 in, fp32 out ----------
// 64x64 tile, BK=32, 4 waves (each wave: 32x32 via 2x2 of 16x16x32 MFMA).
// Register-prefetch pipeline (distance 2): global_load->VGPR for tile k+2 issued
// while tile k computes; ds_write_b128 into padded LDS (row stride 40 elems = 80B,
// 16B-aligned, bank-uniform for both write and fragment-read patterns).
// Grid fixed: 64 M-tiles x 12 N-tiles = 768 blocks (3 blocks/CU). XCD swizzle:
// xcd = blockIdx%8; contiguous 8-M-tile band per XCD, N inner, for L2 locality.
// NOTE: prefetch overruns A/B by <=104 elems on the last iters; all operand
// buffers live in d_ws with a neighbor region after them, so this is safe.
__global__ __launch_bounds__(256) void gemm_p64(
    const unsigned short* __restrict__ A, int lda,
    const unsigned short* __restrict__ B, int ldb,
    float* __restrict__ C, int ldc,
    int K, const float* __restrict__ bias) {
  const int t = threadIdx.x;
  const int b = blockIdx.x;
  const int xcd = b & 7, slot = b >> 3;      // 768 blocks -> slot 0..95
  const int bm = xcd * 8 + slot / 12;        // 0..63
  const int bn = slot % 12;                  // 0..11

  const int wave = t >> 6, lane = t & 63;
  const int quad = lane >> 4, l16 = lane & 15;
  const int wm = (wave >> 1) * 32, wn = (wave & 1) * 32;

  constexpr int LS = 40;  // LDS row stride (elems); 80B = 16B-aligned, conflict-free
  __shared__ __align__(16) unsigned short As[64 * LS];
  __shared__ __align__(16) unsigned short Bs[64 * LS];

  const int srow = t >> 2;          // 0..63
  const int sg   = t & 3;           // col group (8 elems each)
  const unsigned short* Ag = A + (size_t)(bm * 64 + srow) * lda + sg * 8;
  const unsigned short* Bg = B + (size_t)(bn * 64 + srow) * ldb + sg * 8;
  unsigned short* Al = &As[srow * LS + sg * 8];
  unsigned short* Bl = &Bs[srow * LS + sg * 8];

  v4f acc[2][2];
#pragma unroll
  for (int i = 0; i < 2; i++)
#pragma unroll
    for (int j = 0; j < 2; j++) acc[i][j] = (v4f){0.f, 0.f, 0.f, 0.f};

  // prefetch pipeline registers (distance 2)
  uint4 pa0 = *(const uint4*)(Ag);
  uint4 pb0 = *(const uint4*)(Bg);
  uint4 pa1 = *(const uint4*)(Ag + 32);
  uint4 pb1 = *(const uint4*)(Bg + 32);

  // K is a multiple of 64 (2304, 768): process 2 BK-chunks per loop.
  for (int kt = 0; kt < K; kt += 64) {
    // ---- chunk 0 ----
    __syncthreads();                 // prev reads done; LDS reusable
    *(uint4*)Al = pa0;
    *(uint4*)Bl = pb0;
    __syncthreads();
    pa0 = *(const uint4*)(Ag + kt + 64);   // prefetch k+2 (latency hidden by compute below)
    pb0 = *(const uint4*)(Bg + kt + 64);
    {
      v8bf af[2], bf[2];
#pragma unroll
      for (int i = 0; i < 2; i++)
        af[i] = *(const v8bf*)&As[(wm + i * 16 + l16) * LS + quad * 8];
#pragma unroll
      for (int j = 0; j < 2; j++)
        bf[j] = *(const v8bf*)&Bs[(wn + j * 16 + l16) * LS + quad * 8];
#pragma unroll
      for (int i = 0; i < 2; i++)
#pragma unroll
        for (int j = 0; j < 2; j++)
          acc[i][j] = __builtin_amdgcn_mfma_f32_16x16x32_bf16(af[i], bf[j], acc[i][j], 0, 0, 0);
    }
    // ---- chunk 1 ----
    __syncthreads();
    *(uint4*)Al = pa1;
    *(uint4*)Bl = pb1;
    __syncthreads();
    pa1 = *(const uint4*)(Ag + kt + 96);
    pb1 = *(const uint4*)(Bg + kt + 96);
    {
      v8bf af[2], bf[2];
#pragma unroll
      for (int i = 0; i < 2; i++)
        af[i] = *(const v8bf*)&As[(wm + i * 16 + l16) * LS + quad * 8];
#pragma unroll
      for (int j = 0; j < 2; j++)
        bf[j] = *(const v8bf*)&Bs[(wn + j * 16 + l16) * LS + quad * 8];
#pragma unroll
      for (int i = 0; i < 2; i++)
#pragma unroll
        for (int j = 0; j < 2; j++)
          acc[i][j] = __builtin_amdgcn_mfma_f32_16x16x32_bf16(af[i], bf[j], acc[i][j], 0, 0, 0);
    }
  }

  const int row0 = bm * 64 + wm + quad * 4;
  const int col0 = bn * 64 + wn + l16;
#pragma unroll
  for (int j = 0; j < 2; j++) {
    const int col = col0 + j * 16;
    const float bv = bias ? bias[col] : 0.f;
#pragma unroll
    for (int i = 0; i < 2; i++) {
#pragma unroll
      for (int r = 0; r < 4; r++) {
        C[(size_t)(row0 + i * 16 + r) * ldc + col] = acc[i][j][r] + bv;
      }
    }
  }
}

// ---------- quantum head: angles -> PauliZ expectations (closed form) ----------
// expz[0] = prod_{j=1..7} cos(theta_j); expz[w>=1] = prod_{j=0..w} cos(theta_j)
__global__ void quantum_head(const float* __restrict__ proj,
                             const float* __restrict__ b_proj,
                             const float* __restrict__ theta,
                             unsigned short* __restrict__ EZ) {
  const int h = blockIdx.x * blockDim.x + threadIdx.x;  // 0..4096*96-1
  const int token = h / 96;
  const int head = h - token * 96;
  const float* p  = proj + (size_t)token * 768 + head * 8;
  const float* bp = b_proj + head * 8;
  const float4 p0 = *(const float4*)p;
  const float4 p1 = *(const float4*)(p + 4);
  const float4 b0 = *(const float4*)bp;
  const float4 b1 = *(const float4*)(bp + 4);
  float c[8];
  c[0] = cosf(p0.x + b0.x + theta[0]);
  c[1] = cosf(p0.y + b0.y + theta[1]);
  c[2] = cosf(p0.z + b0.z + theta[2]);
  c[3] = cosf(p0.w + b0.w + theta[3]);
  c[4] = cosf(p1.x + b1.x + theta[4]);
  c[5] = cosf(p1.y + b1.y + theta[5]);
  c[6] = cosf(p1.z + b1.z + theta[6]);
  c[7] = cosf(p1.w + b1.w + theta[7]);
  float e[8];
  e[0] = c[1] * c[2] * c[3] * c[4] * c[5] * c[6] * c[7];
  float pr = c[0];
#pragma unroll
  for (int w = 1; w < 8; w++) { pr *= c[w]; e[w] = pr; }
  us8 ov;
#pragma unroll
  for (int w = 0; w < 8; w++) ov[w] = f2bf(e[w]);
  *(us8*)(EZ + (size_t)h * 8) = ov;
}

// ---------- launch ----------
extern "C" void kernel_launch(void* const* d_in, const int* in_sizes, int n_in,
                              void* d_out, int out_size, void* d_ws, size_t ws_size,
                              hipStream_t stream) {
  const float* x     = (const float*)d_in[0];
  const float* Wp    = (const float*)d_in[1];
  const float* bp    = (const float*)d_in[2];
  const float* theta = (const float*)d_in[3];
  const float* Wcf   = (const float*)d_in[4];
  const float* bc    = (const float*)d_in[5];
  float* out = (float*)d_out;

  const int M = 4096, E = 768;

  unsigned short* XC = (unsigned short*)d_ws;        // [4096][2304] bf16  (x: hi|lo|hi)
  unsigned short* WC = XC + (size_t)M * 2304;        // [768][2304] bf16   (Wp: hi|hi|lo)
  unsigned short* WB = WC + (size_t)E * 2304;        // [768][768] bf16    (W_comb)
  unsigned short* EZ = WB + (size_t)E * E;           // [4096][768] bf16   (expz)
  float* proj        = (float*)(EZ + (size_t)M * E); // [4096][768] fp32

  // conversions
  split_hl<<<3072, 256, 0, stream>>>((const float4*)x, XC, 192, 1);   // 4096*768/4 threads
  split_hl<<<576, 256, 0, stream>>>((const float4*)Wp, WC, 192, 2);   // 768*768/4
  conv_bf16<<<576, 256, 0, stream>>>((const float4*)Wcf, (ushort4*)WB);

  // GEMM1: proj = x @ Wp^T   (hi/lo via K-concat, K=2304)  64x12 tiles = 768 blocks
  gemm_p64<<<768, 256, 0, stream>>>(XC, 2304, WC, 2304, proj, 768, 2304, nullptr);

  // quantum head: angles = proj + b_proj + theta -> expz (bf16)
  quantum_head<<<1536, 256, 0, stream>>>(proj, bp, theta, EZ);

  // GEMM2: out = expz @ Wc^T + bc   (K=768)  768 blocks
  gemm_p64<<<768, 256, 0, stream>>>(EZ, 768, WB, 768, out, 768, 768, bc);
}